// Round 14
// baseline (324.122 us; speedup 1.0000x reference)
//
#include <hip/hip_runtime.h>

// NeighborRoutingAgg: N=50000, M=32, D=128, 3 routing iters.
// Round 14 (= r13 resubmit; broker timeout): retest r10's 2-buffer rotated
// pipeline WITHOUT its residency confound. r10 ran 2048 blocks at VGPR~104 ->
// only ~1024 co-resident, rest serialized (the 137-143us regression). r12
// proved time tracks resident waves; VALU-work-time identical across r10/r12.
// Now: 1024 blocks (= 4 blocks/CU x 256 CUs at 4 waves/SIMD),
// launch_bounds(256,4), persistent grid-stride rotation: gather(next) +
// nb-index(next+1) in flight under compute(current). ~12 nodes/wave.
// Math identical (absmax 1.95e-3).

#define M_NB 32
#define D_DIM 128
#define EPSN 1e-12f

typedef float f32x2 __attribute__((ext_vector_type(2)));

__device__ __forceinline__ unsigned int pack_bf16(float a, float b) {
    unsigned int ba = __builtin_bit_cast(unsigned int, a);
    unsigned int bb = __builtin_bit_cast(unsigned int, b);
    unsigned int ra = (ba + 0x7fffu + ((ba >> 16) & 1u)) >> 16;          // low 16
    unsigned int rb = (bb + 0x7fffu + ((bb >> 16) & 1u)) & 0xffff0000u;  // high 16
    return ra | rb;
}

// ---------- Kernel A: normalized-x bf16 table + invn. Grid-stride, 2 rows/wave.
__global__ __launch_bounds__(256) void prep_kernel(const float* __restrict__ x,
                                                   unsigned int* __restrict__ xnb,
                                                   float* __restrict__ invn, int n) {
    int wid  = (int)((blockIdx.x * blockDim.x + threadIdx.x) >> 6);
    int lane = threadIdx.x & 63;
    int h    = lane >> 5;      // half-wave owns one row
    int l5   = lane & 31;      // lane within half: dims 4*l5 .. 4*l5+3
    int nw   = (int)((gridDim.x * blockDim.x) >> 6);
    int stride = nw * 2;

    for (int row = wid * 2 + h; row < n; row += stride) {
        float4 v = *reinterpret_cast<const float4*>(x + (size_t)row * D_DIM + l5 * 4);
        float s = v.x * v.x + v.y * v.y + v.z * v.z + v.w * v.w;
        #pragma unroll
        for (int off = 1; off <= 16; off <<= 1) s += __shfl_xor(s, off);  // stays in half
        float inv = 1.0f / fmaxf(sqrtf(s), EPSN);
        if (l5 == 0) invn[row] = inv;
        uint2 w;
        w.x = pack_bf16(v.x * inv, v.y * inv);
        w.y = pack_bf16(v.z * inv, v.w * inv);
        *reinterpret_cast<uint2*>(xnb + (size_t)row * 64 + l5 * 2) = w;
    }
}

// ---------- routing helpers ----------

__device__ __forceinline__ int load_idx(const int* __restrict__ nb, bool is64,
                                        int node, int lane) {
    size_t base = (size_t)node * M_NB + (lane & 31);
    return (is64 ? nb[2 * base] : nb[base]) - 1;
}

__device__ __forceinline__ void load_data(const unsigned int* __restrict__ xnb,
                                          const float* __restrict__ x,
                                          const float* __restrict__ invn,
                                          int node, int j, int g, int t,
                                          uint4 (&zp)[8], f32x2 (&xn2)[4]) {
    #pragma unroll
    for (int i = 0; i < 8; ++i) {
        int jm = __shfl(j, i * 4 + g);
        zp[i] = *reinterpret_cast<const uint4*>(xnb + (size_t)jm * 64 + t * 4);
    }
    float4 a = *reinterpret_cast<const float4*>(x + (size_t)node * D_DIM + t * 8);
    float4 b = *reinterpret_cast<const float4*>(x + (size_t)node * D_DIM + t * 8 + 4);
    float inv = invn[node];
    xn2[0] = (f32x2){a.x * inv, a.y * inv};
    xn2[1] = (f32x2){a.z * inv, a.w * inv};
    xn2[2] = (f32x2){b.x * inv, b.y * inv};
    xn2[3] = (f32x2){b.z * inv, b.w * inv};
}

__device__ __forceinline__ void compute_store(const uint4 (&zp)[8], const f32x2 (&xn2)[4],
                                              float* __restrict__ out,
                                              int node, int g, int t) {
    f32x2 z2[8][4];
    #pragma unroll
    for (int i = 0; i < 8; ++i) {
        unsigned int w[4] = { zp[i].x, zp[i].y, zp[i].z, zp[i].w };
        #pragma unroll
        for (int c = 0; c < 4; ++c) {
            z2[i][c] = (f32x2){ __builtin_bit_cast(float, w[c] << 16),
                                __builtin_bit_cast(float, w[c] & 0xffff0000u) };
        }
    }
    f32x2 u2[4];
    #pragma unroll
    for (int c = 0; c < 4; ++c) {
        f32x2 s = (f32x2){0.f, 0.f};
        #pragma unroll
        for (int i = 0; i < 8; ++i) s += z2[i][c];
        s.x += __shfl_xor(s.x, 16);  s.y += __shfl_xor(s.y, 16);
        s.x += __shfl_xor(s.x, 32);  s.y += __shfl_xor(s.y, 32);
        u2[c] = s * (1.0f / M_NB) + xn2[c];
    }
    {
        f32x2 q = u2[0] * u2[0] + u2[1] * u2[1] + u2[2] * u2[2] + u2[3] * u2[3];
        float sq = q.x + q.y;
        #pragma unroll
        for (int off = 1; off <= 8; off <<= 1) sq += __shfl_xor(sq, off);
        float scale = sq / ((sq + 1.0f) * fmaxf(sqrtf(sq), EPSN));
        #pragma unroll
        for (int c = 0; c < 4; ++c) u2[c] *= scale;
    }
    #pragma unroll
    for (int it = 1; it < 3; ++it) {
        float p[8];
        #pragma unroll
        for (int i = 0; i < 8; ++i) {
            f32x2 a = z2[i][0] * u2[0];
            a += z2[i][1] * u2[1];
            a += z2[i][2] * u2[2];
            a += z2[i][3] * u2[3];
            float pd = a.x + a.y;
            #pragma unroll
            for (int off = 1; off <= 8; off <<= 1) pd += __shfl_xor(pd, off);
            p[i] = pd;
        }
        float mx = p[0];
        #pragma unroll
        for (int i = 1; i < 8; ++i) mx = fmaxf(mx, p[i]);
        mx = fmaxf(mx, __shfl_xor(mx, 16));
        mx = fmaxf(mx, __shfl_xor(mx, 32));
        float sum = 0.f;
        #pragma unroll
        for (int i = 0; i < 8; ++i) { p[i] = __expf(p[i] - mx); sum += p[i]; }
        sum += __shfl_xor(sum, 16);
        sum += __shfl_xor(sum, 32);
        float rs = 1.0f / sum;
        #pragma unroll
        for (int c = 0; c < 4; ++c) {
            f32x2 a = (f32x2){0.f, 0.f};
            #pragma unroll
            for (int i = 0; i < 8; ++i) {
                f32x2 pv = (f32x2){p[i], p[i]};
                a += pv * z2[i][c];
            }
            a.x += __shfl_xor(a.x, 16);  a.y += __shfl_xor(a.y, 16);
            a.x += __shfl_xor(a.x, 32);  a.y += __shfl_xor(a.y, 32);
            u2[c] = a * rs + xn2[c];
        }
        if (it < 2) {
            f32x2 q = u2[0] * u2[0] + u2[1] * u2[1] + u2[2] * u2[2] + u2[3] * u2[3];
            float sq = q.x + q.y;
            #pragma unroll
            for (int off = 1; off <= 8; off <<= 1) sq += __shfl_xor(sq, off);
            float scale = sq / ((sq + 1.0f) * fmaxf(sqrtf(sq), EPSN));
            #pragma unroll
            for (int c = 0; c < 4; ++c) u2[c] *= scale;
        }
    }
    if (g == 0) {
        *reinterpret_cast<float4*>(out + (size_t)node * D_DIM + t * 8) =
            make_float4(u2[0].x, u2[0].y, u2[1].x, u2[1].y);
    } else if (g == 1) {
        *reinterpret_cast<float4*>(out + (size_t)node * D_DIM + t * 8 + 4) =
            make_float4(u2[2].x, u2[2].y, u2[3].x, u2[3].y);
    }
}

// ---------- Kernel B: routing, persistent 2-stage rotated pipeline ----------
__global__ __launch_bounds__(256, 4) void routing_bf16_kernel(const float* __restrict__ x,
                                                              const int* __restrict__ nb,
                                                              const unsigned int* __restrict__ xnb,
                                                              const float* __restrict__ invn,
                                                              float* __restrict__ out, int n) {
    int wid  = (int)((blockIdx.x * blockDim.x + threadIdx.x) >> 6);
    int lane = threadIdx.x & 63;
    int g = lane >> 4, t = lane & 15;
    int nw  = (int)((gridDim.x * blockDim.x) >> 6);
    int nw2 = nw * 2;

    int probe = nb[lane];
    bool sig  = (lane & 1) ? (probe == 0) : (probe != 0);
    bool is64 = __all(sig);

    int kA = wid;
    if (kA >= n) return;
    uint4 zpA[8], zpB[8];
    f32x2 xnA[4], xnB[4];

    int jA = load_idx(nb, is64, kA, lane);
    load_data(xnb, x, invn, kA, jA, g, t, zpA, xnA);
    int kB = kA + nw;
    int jB = (kB < n) ? load_idx(nb, is64, kB, lane) : 0;

    while (true) {
        // stage B's gather + prefetch index for A's next node, then compute A
        if (kB < n) load_data(xnb, x, invn, kB, jB, g, t, zpB, xnB);
        int kA2 = kA + nw2;
        if (kA2 < n) jA = load_idx(nb, is64, kA2, lane);
        compute_store(zpA, xnA, out, kA, g, t);
        kA = kA2;
        if (kB >= n) break;
        // stage A's gather + prefetch index for B's next node, then compute B
        if (kA < n) load_data(xnb, x, invn, kA, jA, g, t, zpA, xnA);
        int kB2 = kB + nw2;
        if (kB2 < n) jB = load_idx(nb, is64, kB2, lane);
        compute_store(zpB, xnB, out, kB, g, t);
        kB = kB2;
        if (kA >= n) break;
    }
}

// ---------- fallback f32 path (round-4, proven) ----------

__global__ __launch_bounds__(256) void invnorm_kernel(const float* __restrict__ x,
                                                      float* __restrict__ invn, int n) {
    int row  = (int)((blockIdx.x * blockDim.x + threadIdx.x) >> 6);
    int lane = threadIdx.x & 63;
    if (row >= n) return;
    float2 v = *reinterpret_cast<const float2*>(x + (size_t)row * D_DIM + 2 * lane);
    float s = v.x * v.x + v.y * v.y;
    #pragma unroll
    for (int off = 32; off; off >>= 1) s += __shfl_xor(s, off);
    if (lane == 0) invn[row] = 1.0f / fmaxf(sqrtf(s), EPSN);
}

__global__ __launch_bounds__(256) void routing_kernel(const float* __restrict__ x,
                                                      const int* __restrict__ nb,
                                                      const float* __restrict__ invn,
                                                      float* __restrict__ out, int n) {
    int node = (int)((blockIdx.x * blockDim.x + threadIdx.x) >> 6);
    int lane = threadIdx.x & 63;
    if (node >= n) return;

    int probe = nb[lane];
    bool sig  = (lane & 1) ? (probe == 0) : (probe != 0);
    bool is64 = __all(sig);

    size_t base = (size_t)node * M_NB + (lane & 31);
    int j = (is64 ? nb[2 * base] : nb[base]) - 1;
    float vinv = invn[j];

    float2 z[M_NB];
    #pragma unroll
    for (int m = 0; m < M_NB; ++m) {
        int   jm = __shfl(j, m);
        float im = __shfl(vinv, m);
        float2 v = *reinterpret_cast<const float2*>(x + (size_t)jm * D_DIM + 2 * lane);
        z[m] = make_float2(v.x * im, v.y * im);
    }

    float2 xs = *reinterpret_cast<const float2*>(x + (size_t)node * D_DIM + 2 * lane);
    float  si = invn[node];
    float2 xn = make_float2(xs.x * si, xs.y * si);

    float2 u = make_float2(0.f, 0.f);
    #pragma unroll
    for (int m = 0; m < M_NB; ++m) { u.x += z[m].x; u.y += z[m].y; }
    u.x = u.x * (1.0f / M_NB) + xn.x;
    u.y = u.y * (1.0f / M_NB) + xn.y;
    {
        float sq = u.x * u.x + u.y * u.y;
        #pragma unroll
        for (int off = 32; off; off >>= 1) sq += __shfl_xor(sq, off);
        float scale = sq / ((sq + 1.0f) * fmaxf(sqrtf(sq), EPSN));
        u.x *= scale; u.y *= scale;
    }
    #pragma unroll
    for (int it = 1; it < 3; ++it) {
        float p[M_NB];
        #pragma unroll
        for (int m = 0; m < M_NB; ++m) {
            float tt = z[m].x * u.x + z[m].y * u.y;
            #pragma unroll
            for (int off = 32; off; off >>= 1) tt += __shfl_xor(tt, off);
            p[m] = tt;
        }
        float mx = p[0];
        #pragma unroll
        for (int m = 1; m < M_NB; ++m) mx = fmaxf(mx, p[m]);
        float sum = 0.f;
        #pragma unroll
        for (int m = 0; m < M_NB; ++m) { p[m] = __expf(p[m] - mx); sum += p[m]; }
        float rs = 1.0f / sum;
        float2 acc = make_float2(0.f, 0.f);
        #pragma unroll
        for (int m = 0; m < M_NB; ++m) { acc.x += p[m] * z[m].x; acc.y += p[m] * z[m].y; }
        u.x = acc.x * rs + xn.x;
        u.y = acc.y * rs + xn.y;
        if (it < 2) {
            float sq = u.x * u.x + u.y * u.y;
            #pragma unroll
            for (int off = 32; off; off >>= 1) sq += __shfl_xor(sq, off);
            float scale = sq / ((sq + 1.0f) * fmaxf(sqrtf(sq), EPSN));
            u.x *= scale; u.y *= scale;
        }
    }
    *reinterpret_cast<float2*>(out + (size_t)node * D_DIM + 2 * lane) = u;
}

extern "C" void kernel_launch(void* const* d_in, const int* in_sizes, int n_in,
                              void* d_out, int out_size, void* d_ws, size_t ws_size,
                              hipStream_t stream) {
    const float* x  = (const float*)d_in[0];
    const int*   nb = (const int*)d_in[1];
    float* out = (float*)d_out;

    int n = in_sizes[0] / D_DIM;  // 50000

    size_t xnb_bytes = (size_t)n * D_DIM * 2;  // 12.8 MB
    size_t need = xnb_bytes + (size_t)n * 4;   // + invn

    if (ws_size >= need) {
        unsigned int* xnb = (unsigned int*)d_ws;
        float* invn = (float*)((char*)d_ws + xnb_bytes);
        prep_kernel<<<2048, 256, 0, stream>>>(x, xnb, invn, n);
        // 1024 blocks = 4 blocks/CU x 256 CUs at 4 waves/SIMD (VGPR<=128):
        // ALL waves co-resident -> pipeline runs without grid serialization.
        routing_bf16_kernel<<<1024, 256, 0, stream>>>(x, nb, xnb, invn, out, n);
    } else {
        float* invn = (float*)d_ws;
        int blocks = (n + 3) / 4;
        invnorm_kernel<<<blocks, 256, 0, stream>>>(x, invn, n);
        routing_kernel<<<blocks, 256, 0, stream>>>(x, nb, invn, out, n);
    }
}

// Round 15
// 156.423 us; speedup vs baseline: 2.0721x; 2.0721x over previous
//
#include <hip/hip_runtime.h>

// NeighborRoutingAgg: N=50000, M=32, D=128, 3 routing iters.
// Round 15: REVERT to proven-best r9 body (one-shot 1 wave/node, routing
// 92.9us) after r14's pipeline spilled to scratch (WRITE_SIZE 538MB, 3x
// regression). One additive change: self-term xn now read from the bf16
// table (1 uint4 load) instead of f32 x + invn -> deletes the 25.6MB f32
// stream from routing (FETCH 162->~140MB) and ~10 VALU/wave. Error adds
// only bf16 rounding on xn (~3e-4; absmax 1.95e-3 -> ~2.1e-3, thr 9.2e-3).
// Prep: r12 grid-stride (2048 blocks, 2 rows/wave), invn no longer needed.

#define M_NB 32
#define D_DIM 128
#define EPSN 1e-12f

typedef float f32x2 __attribute__((ext_vector_type(2)));

__device__ __forceinline__ unsigned int pack_bf16(float a, float b) {
    unsigned int ba = __builtin_bit_cast(unsigned int, a);
    unsigned int bb = __builtin_bit_cast(unsigned int, b);
    unsigned int ra = (ba + 0x7fffu + ((ba >> 16) & 1u)) >> 16;          // low 16
    unsigned int rb = (bb + 0x7fffu + ((bb >> 16) & 1u)) & 0xffff0000u;  // high 16
    return ra | rb;
}

// ---------- Kernel A: normalized-x bf16 table. Grid-stride, 2 rows/wave. ----------
__global__ __launch_bounds__(256) void prep_kernel(const float* __restrict__ x,
                                                   unsigned int* __restrict__ xnb, int n) {
    int wid  = (int)((blockIdx.x * blockDim.x + threadIdx.x) >> 6);
    int lane = threadIdx.x & 63;
    int h    = lane >> 5;      // half-wave owns one row
    int l5   = lane & 31;      // lane within half: dims 4*l5 .. 4*l5+3
    int nw   = (int)((gridDim.x * blockDim.x) >> 6);
    int stride = nw * 2;

    for (int row = wid * 2 + h; row < n; row += stride) {
        float4 v = *reinterpret_cast<const float4*>(x + (size_t)row * D_DIM + l5 * 4);
        float s = v.x * v.x + v.y * v.y + v.z * v.z + v.w * v.w;
        #pragma unroll
        for (int off = 1; off <= 16; off <<= 1) s += __shfl_xor(s, off);  // stays in half
        float inv = 1.0f / fmaxf(sqrtf(s), EPSN);
        uint2 w;
        w.x = pack_bf16(v.x * inv, v.y * inv);   // dword 2*l5   : dims 4l5,4l5+1
        w.y = pack_bf16(v.z * inv, v.w * inv);   // dword 2*l5+1 : dims 4l5+2,4l5+3
        *reinterpret_cast<uint2*>(xnb + (size_t)row * 64 + l5 * 2) = w;
    }
}

// ---------- Kernel B: routing. One wave per node (one-shot blocks, r9 config). ----------
__global__ __launch_bounds__(256) void routing_bf16_kernel(const int* __restrict__ nb,
                                                           const unsigned int* __restrict__ xnb,
                                                           float* __restrict__ out, int n) {
    int node = (int)((blockIdx.x * blockDim.x + threadIdx.x) >> 6);
    int lane = threadIdx.x & 63;
    if (node >= n) return;
    int g = lane >> 4, t = lane & 15;

    // x_nb dtype probe (int64-as-int32: odd words all zero; ids are 1..N, never 0)
    int probe = nb[lane];
    bool sig  = (lane & 1) ? (probe == 0) : (probe != 0);
    bool is64 = __all(sig);

    size_t base = (size_t)node * M_NB + (lane & 31);
    int j = (is64 ? nb[2 * base] : nb[base]) - 1;

    // Gather: instruction i loads row 4i+g; lane reads 16B = dims 8t..8t+7 (bf16x8).
    uint4 zp[8];
    #pragma unroll
    for (int i = 0; i < 8; ++i) {
        int jm = __shfl(j, i * 4 + g);
        zp[i] = *reinterpret_cast<const uint4*>(xnb + (size_t)jm * 64 + t * 4);
    }

    // Self xn from the bf16 table (replaces f32 x + invn reads; +~3e-4 error)
    f32x2 xn2[4];
    {
        uint4 sp = *reinterpret_cast<const uint4*>(xnb + (size_t)node * 64 + t * 4);
        unsigned int w[4] = { sp.x, sp.y, sp.z, sp.w };
        #pragma unroll
        for (int c = 0; c < 4; ++c) {
            xn2[c] = (f32x2){ __builtin_bit_cast(float, w[c] << 16),
                              __builtin_bit_cast(float, w[c] & 0xffff0000u) };
        }
    }

    // Unpack bf16 -> f32 (compiler may remat/AGPR-park; accepted per r9)
    f32x2 z2[8][4];
    #pragma unroll
    for (int i = 0; i < 8; ++i) {
        unsigned int w[4] = { zp[i].x, zp[i].y, zp[i].z, zp[i].w };
        #pragma unroll
        for (int c = 0; c < 4; ++c) {
            z2[i][c] = (f32x2){ __builtin_bit_cast(float, w[c] << 16),
                                __builtin_bit_cast(float, w[c] & 0xffff0000u) };
        }
    }

    // ---- it0: u = mean_m(z) + xn (cross-group reduce xor16, xor32) ----
    f32x2 u2[4];
    #pragma unroll
    for (int c = 0; c < 4; ++c) {
        f32x2 s = (f32x2){0.f, 0.f};
        #pragma unroll
        for (int i = 0; i < 8; ++i) s += z2[i][c];
        s.x += __shfl_xor(s.x, 16);  s.y += __shfl_xor(s.y, 16);
        s.x += __shfl_xor(s.x, 32);  s.y += __shfl_xor(s.y, 32);
        u2[c] = s * (1.0f / M_NB) + xn2[c];
    }
    {   // squash
        f32x2 q = u2[0] * u2[0] + u2[1] * u2[1] + u2[2] * u2[2] + u2[3] * u2[3];
        float sq = q.x + q.y;
        #pragma unroll
        for (int off = 1; off <= 8; off <<= 1) sq += __shfl_xor(sq, off);
        float scale = sq / ((sq + 1.0f) * fmaxf(sqrtf(sq), EPSN));
        #pragma unroll
        for (int c = 0; c < 4; ++c) u2[c] *= scale;
    }

    // ---- iterations 1, 2 ----
    #pragma unroll
    for (int it = 1; it < 3; ++it) {
        float p[8];
        #pragma unroll
        for (int i = 0; i < 8; ++i) {
            f32x2 a = z2[i][0] * u2[0];
            a += z2[i][1] * u2[1];
            a += z2[i][2] * u2[2];
            a += z2[i][3] * u2[3];
            float pd = a.x + a.y;
            #pragma unroll
            for (int off = 1; off <= 8; off <<= 1) pd += __shfl_xor(pd, off);
            p[i] = pd;
        }
        float mx = p[0];
        #pragma unroll
        for (int i = 1; i < 8; ++i) mx = fmaxf(mx, p[i]);
        mx = fmaxf(mx, __shfl_xor(mx, 16));
        mx = fmaxf(mx, __shfl_xor(mx, 32));
        float sum = 0.f;
        #pragma unroll
        for (int i = 0; i < 8; ++i) { p[i] = __expf(p[i] - mx); sum += p[i]; }
        sum += __shfl_xor(sum, 16);
        sum += __shfl_xor(sum, 32);
        float rs = 1.0f / sum;
        #pragma unroll
        for (int c = 0; c < 4; ++c) {
            f32x2 a = (f32x2){0.f, 0.f};
            #pragma unroll
            for (int i = 0; i < 8; ++i) {
                f32x2 pv = (f32x2){p[i], p[i]};
                a += pv * z2[i][c];
            }
            a.x += __shfl_xor(a.x, 16);  a.y += __shfl_xor(a.y, 16);
            a.x += __shfl_xor(a.x, 32);  a.y += __shfl_xor(a.y, 32);
            u2[c] = a * rs + xn2[c];
        }
        if (it < 2) {
            f32x2 q = u2[0] * u2[0] + u2[1] * u2[1] + u2[2] * u2[2] + u2[3] * u2[3];
            float sq = q.x + q.y;
            #pragma unroll
            for (int off = 1; off <= 8; off <<= 1) sq += __shfl_xor(sq, off);
            float scale = sq / ((sq + 1.0f) * fmaxf(sqrtf(sq), EPSN));
            #pragma unroll
            for (int c = 0; c < 4; ++c) u2[c] *= scale;
        }
    }

    // write full 512B row via groups 0/1 (static indices)
    if (g == 0) {
        *reinterpret_cast<float4*>(out + (size_t)node * D_DIM + t * 8) =
            make_float4(u2[0].x, u2[0].y, u2[1].x, u2[1].y);
    } else if (g == 1) {
        *reinterpret_cast<float4*>(out + (size_t)node * D_DIM + t * 8 + 4) =
            make_float4(u2[2].x, u2[2].y, u2[3].x, u2[3].y);
    }
}

// ---------- fallback f32 path (round-4, proven) ----------

__global__ __launch_bounds__(256) void invnorm_kernel(const float* __restrict__ x,
                                                      float* __restrict__ invn, int n) {
    int row  = (int)((blockIdx.x * blockDim.x + threadIdx.x) >> 6);
    int lane = threadIdx.x & 63;
    if (row >= n) return;
    float2 v = *reinterpret_cast<const float2*>(x + (size_t)row * D_DIM + 2 * lane);
    float s = v.x * v.x + v.y * v.y;
    #pragma unroll
    for (int off = 32; off; off >>= 1) s += __shfl_xor(s, off);
    if (lane == 0) invn[row] = 1.0f / fmaxf(sqrtf(s), EPSN);
}

__global__ __launch_bounds__(256) void routing_kernel(const float* __restrict__ x,
                                                      const int* __restrict__ nb,
                                                      const float* __restrict__ invn,
                                                      float* __restrict__ out, int n) {
    int node = (int)((blockIdx.x * blockDim.x + threadIdx.x) >> 6);
    int lane = threadIdx.x & 63;
    if (node >= n) return;

    int probe = nb[lane];
    bool sig  = (lane & 1) ? (probe == 0) : (probe != 0);
    bool is64 = __all(sig);

    size_t base = (size_t)node * M_NB + (lane & 31);
    int j = (is64 ? nb[2 * base] : nb[base]) - 1;
    float vinv = invn[j];

    float2 z[M_NB];
    #pragma unroll
    for (int m = 0; m < M_NB; ++m) {
        int   jm = __shfl(j, m);
        float im = __shfl(vinv, m);
        float2 v = *reinterpret_cast<const float2*>(x + (size_t)jm * D_DIM + 2 * lane);
        z[m] = make_float2(v.x * im, v.y * im);
    }

    float2 xs = *reinterpret_cast<const float2*>(x + (size_t)node * D_DIM + 2 * lane);
    float  si = invn[node];
    float2 xn = make_float2(xs.x * si, xs.y * si);

    float2 u = make_float2(0.f, 0.f);
    #pragma unroll
    for (int m = 0; m < M_NB; ++m) { u.x += z[m].x; u.y += z[m].y; }
    u.x = u.x * (1.0f / M_NB) + xn.x;
    u.y = u.y * (1.0f / M_NB) + xn.y;
    {
        float sq = u.x * u.x + u.y * u.y;
        #pragma unroll
        for (int off = 32; off; off >>= 1) sq += __shfl_xor(sq, off);
        float scale = sq / ((sq + 1.0f) * fmaxf(sqrtf(sq), EPSN));
        u.x *= scale; u.y *= scale;
    }
    #pragma unroll
    for (int it = 1; it < 3; ++it) {
        float p[M_NB];
        #pragma unroll
        for (int m = 0; m < M_NB; ++m) {
            float tt = z[m].x * u.x + z[m].y * u.y;
            #pragma unroll
            for (int off = 32; off; off >>= 1) tt += __shfl_xor(tt, off);
            p[m] = tt;
        }
        float mx = p[0];
        #pragma unroll
        for (int m = 1; m < M_NB; ++m) mx = fmaxf(mx, p[m]);
        float sum = 0.f;
        #pragma unroll
        for (int m = 0; m < M_NB; ++m) { p[m] = __expf(p[m] - mx); sum += p[m]; }
        float rs = 1.0f / sum;
        float2 acc = make_float2(0.f, 0.f);
        #pragma unroll
        for (int m = 0; m < M_NB; ++m) { acc.x += p[m] * z[m].x; acc.y += p[m] * z[m].y; }
        u.x = acc.x * rs + xn.x;
        u.y = acc.y * rs + xn.y;
        if (it < 2) {
            float sq = u.x * u.x + u.y * u.y;
            #pragma unroll
            for (int off = 32; off; off >>= 1) sq += __shfl_xor(sq, off);
            float scale = sq / ((sq + 1.0f) * fmaxf(sqrtf(sq), EPSN));
            u.x *= scale; u.y *= scale;
        }
    }
    *reinterpret_cast<float2*>(out + (size_t)node * D_DIM + 2 * lane) = u;
}

extern "C" void kernel_launch(void* const* d_in, const int* in_sizes, int n_in,
                              void* d_out, int out_size, void* d_ws, size_t ws_size,
                              hipStream_t stream) {
    const float* x  = (const float*)d_in[0];
    const int*   nb = (const int*)d_in[1];
    float* out = (float*)d_out;

    int n = in_sizes[0] / D_DIM;  // 50000

    size_t xnb_bytes = (size_t)n * D_DIM * 2;  // 12.8 MB

    if (ws_size >= xnb_bytes) {
        unsigned int* xnb = (unsigned int*)d_ws;
        prep_kernel<<<2048, 256, 0, stream>>>(x, xnb, n);
        int blocks = (n + 3) / 4;  // one-shot, 1 wave/node (r9 proven config)
        routing_bf16_kernel<<<blocks, 256, 0, stream>>>(nb, xnb, out, n);
    } else {
        float* invn = (float*)d_ws;
        int blocks = (n + 3) / 4;
        invnorm_kernel<<<blocks, 256, 0, stream>>>(x, invn, n);
        routing_kernel<<<blocks, 256, 0, stream>>>(x, nb, invn, out, n);
    }
}